// Round 11
// baseline (236.441 us; speedup 1.0000x reference)
//
#include <hip/hip_runtime.h>

#define NBATCH 32
#define NDIM 512
#define NFAST 448
#define NQUAD 112
#define NWAVE 8

// ---- DPP cross-lane primitives ----
// Native DPP-arithmetic forms (gfx9 idiom). Invalid source lanes (no
// bound_ctrl => don't write) keep their value = scan identity. Hazard:
// VALU-write -> DPP-read needs 2 wait states; covered by s_nop or by
// interleaved independent instructions (which do useful work).

// Fused: wave64 inclusive prefix sum of p, with one row's sigmoid prep
// (c2n = rm * rcp(1 + exp2(-log2e * rx)); oc2n = 1 - c2n) interleaved
// into the 6 DPP hazard gaps. Bit-identical math to __expf/rcpf path:
// 0xBFB8AA3B = -log2(e), and -(a*b) == (-b)*a exactly in IEEE mul.
__device__ __forceinline__ void prefix_prep(float& p, float rx, float rm,
                                            float& c2n, float& oc2n) {
  float t0, t1, t2;
  asm("v_mul_f32 %1, 0xbfb8aa3b, %6\n\t"  // t0 = -log2e * rx
      "s_nop 0\n\t"
      "v_add_f32_dpp %0, %0, %0 row_shr:1 row_mask:0xf bank_mask:0xf\n\t"
      "v_exp_f32 %1, %1\n\t"              // t0 = exp2(t0) == expf(-rx)
      "s_nop 0\n\t"
      "v_add_f32_dpp %0, %0, %0 row_shr:2 row_mask:0xf bank_mask:0xf\n\t"
      "v_add_f32 %2, 1.0, %1\n\t"         // t1 = 1 + exp
      "s_nop 0\n\t"
      "v_add_f32_dpp %0, %0, %0 row_shr:4 row_mask:0xf bank_mask:0xf\n\t"
      "v_rcp_f32 %3, %2\n\t"              // t2 = rcp(t1)
      "s_nop 0\n\t"
      "v_add_f32_dpp %0, %0, %0 row_shr:8 row_mask:0xf bank_mask:0xf\n\t"
      "v_mul_f32 %4, %7, %3\n\t"          // c2n = rm * t2
      "s_nop 0\n\t"
      "v_add_f32_dpp %0, %0, %0 row_bcast:15 row_mask:0xa bank_mask:0xf\n\t"
      "v_sub_f32 %5, 1.0, %4\n\t"         // oc2n = 1 - c2n
      "s_nop 0\n\t"
      "v_add_f32_dpp %0, %0, %0 row_bcast:31 row_mask:0xc bank_mask:0xf"
      : "+v"(p), "=&v"(t0), "=&v"(t1), "=&v"(t2), "=&v"(c2n), "=&v"(oc2n)
      : "v"(rx), "v"(rm));
}

// TWO independent inclusive prefix sums, stages interleaved (FULL phase).
__device__ __forceinline__ void prefix_inc2(float& a, float& b) {
  asm("s_nop 1\n\t"
      "v_add_f32_dpp %0, %0, %0 row_shr:1 row_mask:0xf bank_mask:0xf\n\t"
      "v_add_f32_dpp %1, %1, %1 row_shr:1 row_mask:0xf bank_mask:0xf\n\t"
      "s_nop 0\n\t"
      "v_add_f32_dpp %0, %0, %0 row_shr:2 row_mask:0xf bank_mask:0xf\n\t"
      "v_add_f32_dpp %1, %1, %1 row_shr:2 row_mask:0xf bank_mask:0xf\n\t"
      "s_nop 0\n\t"
      "v_add_f32_dpp %0, %0, %0 row_shr:4 row_mask:0xf bank_mask:0xf\n\t"
      "v_add_f32_dpp %1, %1, %1 row_shr:4 row_mask:0xf bank_mask:0xf\n\t"
      "s_nop 0\n\t"
      "v_add_f32_dpp %0, %0, %0 row_shr:8 row_mask:0xf bank_mask:0xf\n\t"
      "v_add_f32_dpp %1, %1, %1 row_shr:8 row_mask:0xf bank_mask:0xf\n\t"
      "s_nop 0\n\t"
      "v_add_f32_dpp %0, %0, %0 row_bcast:15 row_mask:0xa bank_mask:0xf\n\t"
      "v_add_f32_dpp %1, %1, %1 row_bcast:15 row_mask:0xa bank_mask:0xf\n\t"
      "s_nop 0\n\t"
      "v_add_f32_dpp %0, %0, %0 row_bcast:31 row_mask:0xc bank_mask:0xf\n\t"
      "v_add_f32_dpp %1, %1, %1 row_bcast:31 row_mask:0xc bank_mask:0xf\n\t"
      "s_nop 1"
      : "+v"(a), "+v"(b));
}

// wave64 inclusive affine-composition scan: per stage
//   B += dpp(B) * A   (v_fmac, pre-update A == fmaf(A, Be, B))
//   A *= dpp(A)       (v_mul)
// Skipped invalid lanes == compose with identity (1,0).
__device__ __forceinline__ void aff_scan(float& A, float& B) {
  asm("s_nop 1\n\t"
      "v_fmac_f32_dpp %1, %1, %0 row_shr:1 row_mask:0xf bank_mask:0xf\n\t"
      "v_mul_f32_dpp  %0, %0, %0 row_shr:1 row_mask:0xf bank_mask:0xf\n\t"
      "s_nop 0\n\t"
      "v_fmac_f32_dpp %1, %1, %0 row_shr:2 row_mask:0xf bank_mask:0xf\n\t"
      "v_mul_f32_dpp  %0, %0, %0 row_shr:2 row_mask:0xf bank_mask:0xf\n\t"
      "s_nop 0\n\t"
      "v_fmac_f32_dpp %1, %1, %0 row_shr:4 row_mask:0xf bank_mask:0xf\n\t"
      "v_mul_f32_dpp  %0, %0, %0 row_shr:4 row_mask:0xf bank_mask:0xf\n\t"
      "s_nop 0\n\t"
      "v_fmac_f32_dpp %1, %1, %0 row_shr:8 row_mask:0xf bank_mask:0xf\n\t"
      "v_mul_f32_dpp  %0, %0, %0 row_shr:8 row_mask:0xf bank_mask:0xf\n\t"
      "s_nop 0\n\t"
      "v_fmac_f32_dpp %1, %1, %0 row_bcast:15 row_mask:0xa bank_mask:0xf\n\t"
      "v_mul_f32_dpp  %0, %0, %0 row_bcast:15 row_mask:0xa bank_mask:0xf\n\t"
      "s_nop 0\n\t"
      "v_fmac_f32_dpp %1, %1, %0 row_bcast:31 row_mask:0xc bank_mask:0xf\n\t"
      "v_mul_f32_dpp  %0, %0, %0 row_bcast:31 row_mask:0xc bank_mask:0xf\n\t"
      "s_nop 1"
      : "+v"(A), "+v"(B));
}

// shift one lane up (lane i gets lane i-1); lane 0 receives `fill`
__device__ __forceinline__ float wave_shr1(float x, float fill) {
  return __int_as_float(__builtin_amdgcn_update_dpp(
      __float_as_int(fill), __float_as_int(x), 0x138 /*wave_shr:1*/, 0xf, 0xf,
      false));
}

// Workgroup barrier WITHOUT the vmcnt(0) drain __syncthreads() emits.
__device__ __forceinline__ void wg_barrier() {
  asm volatile("s_waitcnt lgkmcnt(0)" ::: "memory");
  __builtin_amdgcn_s_barrier();
  asm volatile("" ::: "memory");
}

// R24: R23's quad systolic (PROVEN math, verbatim order) with (a)
// skew-1 + barrier-per-quad-step: wave w does quad q at t = q + w, 119
// live steps vs 126 (record written by wave w-1 at step q+w-1, read by
// wave w at q+w, one barrier between -> visibility proof intact); and
// (b) the next-quad sigmoid prep fused INTO each row's prefix-scan asm
// hazard slots (prefix_prep) — the compiler can't schedule across asm
// boundaries, so the fillers turn forced s_nop stalls into useful work.
// All FP values and order bit-identical to R23 => absmax unchanged.
__global__ __launch_bounds__(512, 2)
void sb_kernel(const float* __restrict__ x, const float* __restrict__ xm,
               float* __restrict__ out) {
  const int tid = (int)threadIdx.x;
  const int lane = tid & 63;
  const int w = __builtin_amdgcn_readfirstlane(tid >> 6);  // wave id 0..7
  const size_t base =
      (size_t)blockIdx.x * NDIM * NDIM + (size_t)(w * 64 + lane);
  const float* xb = x + base;
  const float* mb = xm + base;
  float* ob = out + base;

  __shared__ float4 recs[NFAST];              // rolling cum {A,B,cumPA,-}
  __shared__ alignas(16) float ex_sa[NWAVE];  // FULL-mode exchange
  __shared__ alignas(16) float ex_S[NWAVE];
  __shared__ alignas(16) float ex_A[NWAVE];
  __shared__ alignas(16) float ex_B[NWAVE];

  // per-lane state
  float w8, t8;  // stick remainder + current row's scan input
  float c2_0, oc2_0, c2_1, oc2_1, c2_2, oc2_2, c2_3, oc2_3;  // quad consts
  float c1, c2, oc2;  // FULL-phase per-row constants
  float fu = 0.0f, S = 0.0f;

  // ---- prologue: rows 0..3 direct (current quad constants); quad 1
  // (rows 4..7) into the slot that is the READ slot at the wave's first
  // active step t = w (k = t&1): B for even w, A for odd w. Slot
  // discipline: at step t (k = t&1), write quad q+2 into slot[k], prep
  // quad q+1 from slot[k^1]; load->prep distance = 1 step. ----
  float X0 = xb[0], X1 = xb[NDIM], X2 = xb[2 * NDIM], X3 = xb[3 * NDIM];
  float M0 = mb[0], M1 = mb[NDIM], M2 = mb[2 * NDIM], M3 = mb[3 * NDIM];
  float q1x0 = xb[4 * NDIM], q1x1 = xb[5 * NDIM], q1x2 = xb[6 * NDIM],
        q1x3 = xb[7 * NDIM];
  float q1m0 = mb[4 * NDIM], q1m1 = mb[5 * NDIM], q1m2 = mb[6 * NDIM],
        q1m3 = mb[7 * NDIM];
  float Ax0 = q1x0, Ax1 = q1x1, Ax2 = q1x2, Ax3 = q1x3;
  float Am0 = q1m0, Am1 = q1m1, Am2 = q1m2, Am3 = q1m3;
  float Bx0 = q1x0, Bx1 = q1x1, Bx2 = q1x2, Bx3 = q1x3;
  float Bm0 = q1m0, Bm1 = q1m1, Bm2 = q1m2, Bm3 = q1m3;
  // (both slots initialized to quad 1; the wrong-parity copy is dead —
  // it is overwritten by the first active step's loads before any prep
  // reads it at the matching parity)

  {  // prep rows 0..3 constants; row-0 scan input (w8 == 1)
    float s0 = __builtin_amdgcn_rcpf(1.0f + __expf(-X0));
    float s1 = __builtin_amdgcn_rcpf(1.0f + __expf(-X1));
    float s2 = __builtin_amdgcn_rcpf(1.0f + __expf(-X2));
    float s3 = __builtin_amdgcn_rcpf(1.0f + __expf(-X3));
    c2_0 = M0 * s0;
    oc2_0 = 1.0f - c2_0;
    c2_1 = M1 * s1;
    oc2_1 = 1.0f - c2_1;
    c2_2 = M2 * s2;
    oc2_2 = 1.0f - c2_2;
    c2_3 = M3 * s3;
    oc2_3 = 1.0f - c2_3;
    w8 = 1.0f;
    t8 = c2_0;
  }

  // running pointers (strength-reduced; inactive waves never deref).
  // At wave w's first active step t = w: load quad 2 (row 8), store
  // row 0. px tracks the k=0 position of the current 2-step pair.
  const float* px = xb + (long)(8 - 4 * w) * NDIM;
  const float* pm = mb + (long)(8 - 4 * w) * NDIM;
  float* po = ob - (long)(4 * w) * NDIM;

  // ---- one row of proven math (fused prefix+prep, then affine scan) --
  auto row_fast = [&](int m, const float4& r, float c2r, float oc2r,
                      float rx, float rm, float& c2n, float& oc2n,
                      float* pO) {
    float PA = t8;
    prefix_prep(PA, rx, rm, c2n, oc2n);  // PA = prefix_inc(t8) + prep
    float uin = fmaxf(1.0f - (r.z + (PA - t8)), 0.0f);
    bool pW = w8 < uin;
    float A = pW ? 1.0f : oc2r;
    float Bv = pW ? (-t8) : 0.0f;
    aff_scan(A, Bv);
    float Aex = wave_shr1(A, 1.0f);
    float Bex = wave_shr1(Bv, 0.0f);
    if (w < NWAVE - 1 && lane == 63)
      recs[m] = make_float4(A * r.x, fmaf(A, r.y, Bv), r.z + PA, 0.0f);
    float E = r.x + r.y;
    float e = fminf(fmaxf(fmaf(Aex, E, Bex), 0.0f), 1.0f);
    float p = c2r * fminf(e, w8);
    w8 -= p;
    *pO = p;
  };

  // ---- 4-row systolic step (barrier after every step) ----
  auto quad_step = [&](int t, int k, float& WX0, float& WX1, float& WX2,
                       float& WX3, float& WM0, float& WM1, float& WM2,
                       float& WM3, const float& RX0, const float& RX1,
                       const float& RX2, const float& RX3, const float& RM0,
                       const float& RM1, const float& RM2, const float& RM3) {
    const int q = t - w;
    if ((unsigned)q < (unsigned)NQUAD) {  // wave-uniform
      const int m = 4 * q;
      // read all 4 predecessor cum records (published 1 step ago,
      // ordered by the intervening barrier)
      float4 r0 = make_float4(1.0f, 0.0f, 0.0f, 0.0f);
      float4 r1 = r0, r2 = r0, r3 = r0;
      if (w > 0) {
        r0 = recs[m];
        r1 = recs[m + 1];
        r2 = recs[m + 2];
        r3 = recs[m + 3];
      }
      // issue next quad's global loads (quad q+2) into slot registers
      const float* pxk = px + (size_t)(4 * k) * NDIM;
      const float* pmk = pm + (size_t)(4 * k) * NDIM;
      WX0 = pxk[0];
      WX1 = pxk[NDIM];
      WX2 = pxk[2 * NDIM];
      WX3 = pxk[3 * NDIM];
      WM0 = pmk[0];
      WM1 = pmk[NDIM];
      WM2 = pmk[2 * NDIM];
      WM3 = pmk[3 * NDIM];

      // quad q+1 prep is fused into the 4 prefix scans below
      float c2n0, oc2n0, c2n1, oc2n1, c2n2, oc2n2, c2n3, oc2n3;
      float* pok = po + (size_t)(4 * k) * NDIM;
      row_fast(m + 0, r0, c2_0, oc2_0, RX0, RM0, c2n0, oc2n0, pok);
      t8 = c2_1 * w8;
      row_fast(m + 1, r1, c2_1, oc2_1, RX1, RM1, c2n1, oc2n1, pok + NDIM);
      t8 = c2_2 * w8;
      row_fast(m + 2, r2, c2_2, oc2_2, RX2, RM2, c2n2, oc2n2,
               pok + 2 * NDIM);
      t8 = c2_3 * w8;
      row_fast(m + 3, r3, c2_3, oc2_3, RX3, RM3, c2n3, oc2n3,
               pok + 3 * NDIM);
      // next quad's scan input + constants
      t8 = c2n0 * w8;
      c2_0 = c2n0;
      oc2_0 = oc2n0;
      c2_1 = c2n1;
      oc2_1 = oc2n1;
      c2_2 = c2n2;
      oc2_2 = oc2n2;
      c2_3 = c2n3;
      oc2_3 = oc2n3;
    }
    wg_barrier();
  };

  // fast phase: steps t = 0 .. 119 (wave w active for t in [w, w+112))
#pragma unroll 1
  for (int t = 0; t < NQUAD + NWAVE; t += 2) {
    quad_step(t + 0, 0, Ax0, Ax1, Ax2, Ax3, Am0, Am1, Am2, Am3, Bx0, Bx1, Bx2,
              Bx3, Bm0, Bm1, Bm2, Bm3);
    quad_step(t + 1, 1, Bx0, Bx1, Bx2, Bx3, Bm0, Bm1, Bm2, Bm3, Ax0, Ax1, Ax2,
              Ax3, Am0, Am1, Am2, Am3);
    px += 8 * NDIM;
    pm += 8 * NDIM;
    po += 8 * NDIM;
  }
  // all waves synced by the final step barrier; recs no longer used.
  // c2_0..3 now hold rows 448..451 constants (prepped at q=111);
  // t8 = c2(448) * w8 from the last fast step's tail.

  // ---- bridge: row-448 constants + fu/S; reload rows 449..451 into
  // FULL-phase single-row slots (L2-hot, one-time). ----
  float fx0, fm0, fx1, fm1, fx2, fm2, fx3, fm3;
  {
    float m448 = mb[(size_t)448 * NDIM];
    fx1 = xb[(size_t)449 * NDIM];
    fm1 = mb[(size_t)449 * NDIM];
    fx2 = xb[(size_t)450 * NDIM];
    fm2 = mb[(size_t)450 * NDIM];
    fx3 = xb[(size_t)451 * NDIM];
    fm3 = mb[(size_t)451 * NDIM];
    fx0 = fx1;  // defined; overwritten at m=448 step
    fm0 = fm1;
    c2 = c2_0;
    oc2 = oc2_0;
    c1 = m448 - c2;
    float om = 1.0f - m448;
    fu = fmaxf(w8 - om, 0.0f);
    S = fu;
  }

  // ---- FULL row body: proven 2-barrier exchange (backward dep on S) ----
  auto row_full = [&](int m, float& WX, float& WM, const float& RX,
                      const float& RM) {
    const size_t nro = (size_t)((m + 4) & (NDIM - 1)) * NDIM;
    WX = xb[nro];
    WM = mb[nro];

    // local wave scans (chain head); independent scans interleaved
    float PS = S, PA = t8;
    prefix_inc2(PS, PA);

    if (lane == 63) {
      ex_sa[w] = PA;  // wave-inclusive totals
      ex_S[w] = PS;
    }
    wg_barrier();  // bar1: publish scan totals

    float4 sl = *(const float4*)&ex_sa[0];
    float4 sh = *(const float4*)&ex_sa[4];
    float4 Sl = *(const float4*)&ex_S[0];
    float4 Sh = *(const float4*)&ex_S[4];
    float off_sa = 0.0f, off_S = 0.0f;
    if (w > 0) { off_sa += sl.x; off_S += Sl.x; }
    if (w > 1) { off_sa += sl.y; off_S += Sl.y; }
    if (w > 2) { off_sa += sl.z; off_S += Sl.z; }
    if (w > 3) { off_sa += sl.w; off_S += Sl.w; }
    if (w > 4) { off_sa += sh.x; off_S += Sh.x; }
    if (w > 5) { off_sa += sh.y; off_S += Sh.y; }
    if (w > 6) { off_sa += sh.z; off_S += Sh.z; }
    float Tg =
        ((Sl.x + Sl.y) + (Sl.z + Sl.w)) + ((Sh.x + Sh.y) + (Sh.z + Sh.w));

    float uin = fmaxf(1.0f - (off_sa + (PA - t8)), 0.0f);
    float R_ = (Tg - off_S) - PS;  // future mass strictly after this lane
    float nc1m = -c1 * R_;         // per-lane suf == 0 at 1 col/lane

    // branch prediction (1 cell)
    bool pW = w8 < uin;
    float aP = pW ? 1.0f : oc2;
    float bP = pW ? (-t8) : 0.0f;
    bool pL = (uin - R_) > 0.0f;
    if (pL) {
      aP -= c1;
      bP -= nc1m;
    }

    // wave affine scan
    float A = aP, Bv = bP;
    aff_scan(A, Bv);
    float Aex = wave_shr1(A, 1.0f);
    float Bex = wave_shr1(Bv, 0.0f);

    if (lane == 63) {
      ex_A[w] = A;  // wave-inclusive composition
      ex_B[w] = Bv;
    }
    wg_barrier();  // bar2: publish affine totals

    float4 Al = *(const float4*)&ex_A[0];
    float4 Ah = *(const float4*)&ex_A[4];
    float4 Bl = *(const float4*)&ex_B[0];
    float4 Bh = *(const float4*)&ex_B[4];
    float E = 1.0f;
    if (w > 0) E = fmaf(Al.x, E, Bl.x);
    if (w > 1) E = fmaf(Al.y, E, Bl.y);
    if (w > 2) E = fmaf(Al.z, E, Bl.z);
    if (w > 3) E = fmaf(Al.w, E, Bl.w);
    if (w > 4) E = fmaf(Ah.x, E, Bh.x);
    if (w > 5) E = fmaf(Ah.y, E, Bh.y);
    if (w > 6) E = fmaf(Ah.z, E, Bh.z);
    float e = fminf(fmaxf(fmaf(Aex, E, Bex), 0.0f), 1.0f);  // lane entry

    // row m+1 x-only prep (off-chain)
    float sg = __builtin_amdgcn_rcpf(1.0f + __expf(-RX));
    float c2n = RM * sg;
    float oc2n = 1.0f - c2n;
    float c1n = RM - c2n;
    float omn = 1.0f - RM;

    // TRUE-branch output
    float U = fminf(e, w8);
    float g = fmaxf(fmaf(c1, e, nc1m), 0.0f);
    float p = fmaf(c2, U, g);
    w8 -= p;
    ob[(size_t)m * NDIM] = p;

    // next row's scan inputs
    t8 = c2n * w8;
    fu = fmaxf(w8 - omn, 0.0f);
    S = fu;
    c2 = c2n;
    oc2 = oc2n;
    c1 = c1n;
  };

#pragma unroll 1
  for (int m = NFAST; m < NDIM; m += 4) {
    row_full(m + 0, fx0, fm0, fx1, fm1);
    row_full(m + 1, fx1, fm1, fx2, fm2);
    row_full(m + 2, fx2, fm2, fx3, fm3);
    row_full(m + 3, fx3, fm3, fx0, fm0);
  }
}

extern "C" void kernel_launch(void* const* d_in, const int* in_sizes, int n_in,
                              void* d_out, int out_size, void* d_ws,
                              size_t ws_size, hipStream_t stream) {
  const float* x = (const float*)d_in[0];
  const float* xmask = (const float*)d_in[1];
  float* out = (float*)d_out;
  (void)in_sizes;
  (void)n_in;
  (void)out_size;
  (void)d_ws;
  (void)ws_size;
  hipLaunchKernelGGL(sb_kernel, dim3(NBATCH), dim3(512), 0, stream, x, xmask,
                     out);
}

// Round 13
// 235.618 us; speedup vs baseline: 1.0035x; 1.0035x over previous
//
#include <hip/hip_runtime.h>

#define NBATCH 32
#define NDIM 512
#define NFAST 448
#define NOCT 56
#define NWAVE 8

// ---- DPP cross-lane primitives ----
// Native DPP-arithmetic forms (gfx9 idiom). Invalid source lanes (no
// bound_ctrl => don't write) keep their value = scan identity. Hazard:
// VALU-write -> DPP-read needs 2 intervening slots; covered by s_nop or
// by interleaved independent instructions (useful work). Hazard audit:
// per stage the dpp-read of A (mul) sees [filler, fmac] = 2 slots after
// the previous mul wrote A; the dpp-read of B (fmac) sees [mul, filler]
// = 2 slots after the previous fmac wrote B. src1 reads are normal
// (no DPP hazard).

// Fused: wave64 inclusive prefix sum of p, with one row's sigmoid prep
// (c2n = rm * rcp(1 + exp2(-log2e * rx)); oc2n = 1 - c2n) interleaved
// into the 6 DPP hazard gaps. Bit-identical math to __expf/rcpf path.
__device__ __forceinline__ void prefix_prep(float& p, float rx, float rm,
                                            float& c2n, float& oc2n) {
  float t0, t1, t2;
  asm("v_mul_f32 %1, 0xbfb8aa3b, %6\n\t"  // t0 = -log2e * rx
      "s_nop 0\n\t"
      "v_add_f32_dpp %0, %0, %0 row_shr:1 row_mask:0xf bank_mask:0xf\n\t"
      "v_exp_f32 %1, %1\n\t"              // t0 = exp2(t0) == expf(-rx)
      "s_nop 0\n\t"
      "v_add_f32_dpp %0, %0, %0 row_shr:2 row_mask:0xf bank_mask:0xf\n\t"
      "v_add_f32 %2, 1.0, %1\n\t"         // t1 = 1 + exp
      "s_nop 0\n\t"
      "v_add_f32_dpp %0, %0, %0 row_shr:4 row_mask:0xf bank_mask:0xf\n\t"
      "v_rcp_f32 %3, %2\n\t"              // t2 = rcp(t1)
      "s_nop 0\n\t"
      "v_add_f32_dpp %0, %0, %0 row_shr:8 row_mask:0xf bank_mask:0xf\n\t"
      "v_mul_f32 %4, %7, %3\n\t"          // c2n = rm * t2
      "s_nop 0\n\t"
      "v_add_f32_dpp %0, %0, %0 row_bcast:15 row_mask:0xa bank_mask:0xf\n\t"
      "v_sub_f32 %5, 1.0, %4\n\t"         // oc2n = 1 - c2n
      "s_nop 0\n\t"
      "v_add_f32_dpp %0, %0, %0 row_bcast:31 row_mask:0xc bank_mask:0xf"
      : "+v"(p), "=&v"(t0), "=&v"(t1), "=&v"(t2), "=&v"(c2n), "=&v"(oc2n)
      : "v"(rx), "v"(rm));
}

// TWO independent inclusive prefix sums, stages interleaved (FULL phase).
__device__ __forceinline__ void prefix_inc2(float& a, float& b) {
  asm("s_nop 1\n\t"
      "v_add_f32_dpp %0, %0, %0 row_shr:1 row_mask:0xf bank_mask:0xf\n\t"
      "v_add_f32_dpp %1, %1, %1 row_shr:1 row_mask:0xf bank_mask:0xf\n\t"
      "s_nop 0\n\t"
      "v_add_f32_dpp %0, %0, %0 row_shr:2 row_mask:0xf bank_mask:0xf\n\t"
      "v_add_f32_dpp %1, %1, %1 row_shr:2 row_mask:0xf bank_mask:0xf\n\t"
      "s_nop 0\n\t"
      "v_add_f32_dpp %0, %0, %0 row_shr:4 row_mask:0xf bank_mask:0xf\n\t"
      "v_add_f32_dpp %1, %1, %1 row_shr:4 row_mask:0xf bank_mask:0xf\n\t"
      "s_nop 0\n\t"
      "v_add_f32_dpp %0, %0, %0 row_shr:8 row_mask:0xf bank_mask:0xf\n\t"
      "v_add_f32_dpp %1, %1, %1 row_shr:8 row_mask:0xf bank_mask:0xf\n\t"
      "s_nop 0\n\t"
      "v_add_f32_dpp %0, %0, %0 row_bcast:15 row_mask:0xa bank_mask:0xf\n\t"
      "v_add_f32_dpp %1, %1, %1 row_bcast:15 row_mask:0xa bank_mask:0xf\n\t"
      "s_nop 0\n\t"
      "v_add_f32_dpp %0, %0, %0 row_bcast:31 row_mask:0xc bank_mask:0xf\n\t"
      "v_add_f32_dpp %1, %1, %1 row_bcast:31 row_mask:0xc bank_mask:0xf\n\t"
      "s_nop 1"
      : "+v"(a), "+v"(b));
}

// wave64 inclusive affine-composition scan (FULL phase; plain).
__device__ __forceinline__ void aff_scan(float& A, float& B) {
  asm("s_nop 1\n\t"
      "v_fmac_f32_dpp %1, %1, %0 row_shr:1 row_mask:0xf bank_mask:0xf\n\t"
      "v_mul_f32_dpp  %0, %0, %0 row_shr:1 row_mask:0xf bank_mask:0xf\n\t"
      "s_nop 0\n\t"
      "v_fmac_f32_dpp %1, %1, %0 row_shr:2 row_mask:0xf bank_mask:0xf\n\t"
      "v_mul_f32_dpp  %0, %0, %0 row_shr:2 row_mask:0xf bank_mask:0xf\n\t"
      "s_nop 0\n\t"
      "v_fmac_f32_dpp %1, %1, %0 row_shr:4 row_mask:0xf bank_mask:0xf\n\t"
      "v_mul_f32_dpp  %0, %0, %0 row_shr:4 row_mask:0xf bank_mask:0xf\n\t"
      "s_nop 0\n\t"
      "v_fmac_f32_dpp %1, %1, %0 row_shr:8 row_mask:0xf bank_mask:0xf\n\t"
      "v_mul_f32_dpp  %0, %0, %0 row_shr:8 row_mask:0xf bank_mask:0xf\n\t"
      "s_nop 0\n\t"
      "v_fmac_f32_dpp %1, %1, %0 row_bcast:15 row_mask:0xa bank_mask:0xf\n\t"
      "v_mul_f32_dpp  %0, %0, %0 row_bcast:15 row_mask:0xa bank_mask:0xf\n\t"
      "s_nop 0\n\t"
      "v_fmac_f32_dpp %1, %1, %0 row_bcast:31 row_mask:0xc bank_mask:0xf\n\t"
      "v_mul_f32_dpp  %0, %0, %0 row_bcast:31 row_mask:0xc bank_mask:0xf\n\t"
      "s_nop 1"
      : "+v"(A), "+v"(B));
}

// Fast-path affine scan with two independent adds (E = rx+ry, the row
// entry; P = rz+PA, the record's cumPA) filling hazard gaps. Same scan
// math/order as aff_scan => bit-identical; fillers are the same ops the
// open code used to execute.
__device__ __forceinline__ void aff_scan_f(float& A, float& B, float& E,
                                           float& P, float rx, float ry,
                                           float rz, float PA) {
  asm("s_nop 1\n\t"
      "v_fmac_f32_dpp %1, %1, %0 row_shr:1 row_mask:0xf bank_mask:0xf\n\t"
      "v_mul_f32_dpp  %0, %0, %0 row_shr:1 row_mask:0xf bank_mask:0xf\n\t"
      "v_add_f32 %2, %4, %5\n\t"  // E = rx + ry
      "v_fmac_f32_dpp %1, %1, %0 row_shr:2 row_mask:0xf bank_mask:0xf\n\t"
      "v_mul_f32_dpp  %0, %0, %0 row_shr:2 row_mask:0xf bank_mask:0xf\n\t"
      "v_add_f32 %3, %6, %7\n\t"  // P = rz + PA
      "v_fmac_f32_dpp %1, %1, %0 row_shr:4 row_mask:0xf bank_mask:0xf\n\t"
      "v_mul_f32_dpp  %0, %0, %0 row_shr:4 row_mask:0xf bank_mask:0xf\n\t"
      "s_nop 0\n\t"
      "v_fmac_f32_dpp %1, %1, %0 row_shr:8 row_mask:0xf bank_mask:0xf\n\t"
      "v_mul_f32_dpp  %0, %0, %0 row_shr:8 row_mask:0xf bank_mask:0xf\n\t"
      "s_nop 0\n\t"
      "v_fmac_f32_dpp %1, %1, %0 row_bcast:15 row_mask:0xa bank_mask:0xf\n\t"
      "v_mul_f32_dpp  %0, %0, %0 row_bcast:15 row_mask:0xa bank_mask:0xf\n\t"
      "s_nop 0\n\t"
      "v_fmac_f32_dpp %1, %1, %0 row_bcast:31 row_mask:0xc bank_mask:0xf\n\t"
      "v_mul_f32_dpp  %0, %0, %0 row_bcast:31 row_mask:0xc bank_mask:0xf"
      : "+v"(A), "+v"(B), "=&v"(E), "=&v"(P)
      : "v"(rx), "v"(ry), "v"(rz), "v"(PA));
}

// shift one lane up (lane i gets lane i-1); lane 0 receives `fill`
__device__ __forceinline__ float wave_shr1(float x, float fill) {
  return __int_as_float(__builtin_amdgcn_update_dpp(
      __float_as_int(fill), __float_as_int(x), 0x138 /*wave_shr:1*/, 0xf, 0xf,
      false));
}

// Workgroup barrier WITHOUT the vmcnt(0) drain __syncthreads() emits.
__device__ __forceinline__ void wg_barrier() {
  asm volatile("s_waitcnt lgkmcnt(0)" ::: "memory");
  __builtin_amdgcn_s_barrier();
  asm volatile("" ::: "memory");
}

// R25: R24's systolic (PROVEN math, verbatim order) with (a) EIGHT rows
// per step (one record-read window, one load batch, one barrier per 8
// rows; 64 barriers; same skew-1 visibility: record written at step t-1
// is read at step t across one barrier); (b) bit-exact instruction
// cuts: e computed as shr1(fmaf(A,E,Bv), fill=E) — lane-for-lane equal
// to fmaf(Aex,E,Bex) (saves one shift); upper clamp dropped since
// w8 <= 1 always (min(max(e,0),w8) == old min(min(max(e,0),1),w8));
// E and cumPA adds moved into aff-scan hazard gaps. FULL rows (448+)
// keep the R24 2-barrier body unchanged.
__global__ __launch_bounds__(512, 2)
void sb_kernel(const float* __restrict__ x, const float* __restrict__ xm,
               float* __restrict__ out) {
  const int tid = (int)threadIdx.x;
  const int lane = tid & 63;
  const int w = __builtin_amdgcn_readfirstlane(tid >> 6);  // wave id 0..7
  const size_t base =
      (size_t)blockIdx.x * NDIM * NDIM + (size_t)(w * 64 + lane);
  const float* xb = x + base;
  const float* mb = xm + base;
  float* ob = out + base;

  __shared__ float4 recs[NFAST];              // rolling cum {A,B,cumPA,-}
  __shared__ alignas(16) float ex_sa[NWAVE];  // FULL-mode exchange
  __shared__ alignas(16) float ex_S[NWAVE];
  __shared__ alignas(16) float ex_A[NWAVE];
  __shared__ alignas(16) float ex_B[NWAVE];

  // per-lane state
  float w8, t8;            // stick remainder + current row's scan input
  float c2c[8], oc2c[8];   // current octet's constants (const-indexed)
  float c1, c2, oc2;       // FULL-phase per-row constants
  float fu = 0.0f, S = 0.0f;

  // ---- prologue: rows 0..7 direct (current octet constants); octet 1
  // (rows 8..15) into BOTH slots (the wrong-parity copy is dead — it is
  // overwritten by the wave's first active step before any prep reads
  // it at that parity). Slot discipline: at step t (k = t&1), write
  // octet q+2 into slot[k], prep octet q+1 from slot[k^1]. ----
  float Ax[8], Am[8], Bx[8], Bm[8];
  {
    float Xr[8], Mr[8];
#pragma unroll
    for (int i = 0; i < 8; ++i) {
      Xr[i] = xb[(size_t)i * NDIM];
      Mr[i] = mb[(size_t)i * NDIM];
      float xv = xb[(size_t)(8 + i) * NDIM];
      float mv = mb[(size_t)(8 + i) * NDIM];
      Ax[i] = Bx[i] = xv;
      Am[i] = Bm[i] = mv;
    }
#pragma unroll
    for (int i = 0; i < 8; ++i) {
      float sg = __builtin_amdgcn_rcpf(1.0f + __expf(-Xr[i]));
      c2c[i] = Mr[i] * sg;
      oc2c[i] = 1.0f - c2c[i];
    }
    w8 = 1.0f;
    t8 = c2c[0];
  }

  // running pointers (strength-reduced; inactive waves never deref).
  // At wave w's first active step t = w (k = w&1): load octet 2 (row
  // 16), store row 0. pxk = px + 8k*NDIM must equal row 8(t-w)+16:
  // px = xb + (16 - 8w)*NDIM advancing 16*NDIM per 2-step iteration.
  const float* px = xb + (long)(16 - 8 * w) * NDIM;
  const float* pm = mb + (long)(16 - 8 * w) * NDIM;
  float* po = ob - (long)(8 * w) * NDIM;

  // ---- one row of proven math (fused prefix+prep, fused affine) ----
  auto row_fast = [&](int m, const float4& r, float c2r, float oc2r,
                      float rx, float rm, float& c2n, float& oc2n,
                      float* pO) {
    float PA = t8;
    prefix_prep(PA, rx, rm, c2n, oc2n);  // PA = prefix_inc(t8) + prep
    float uin = fmaxf(1.0f - (r.z + (PA - t8)), 0.0f);
    bool pW = w8 < uin;
    float A = pW ? 1.0f : oc2r;
    float Bv = pW ? (-t8) : 0.0f;
    float E, PArec;
    aff_scan_f(A, Bv, E, PArec, r.x, r.y, r.z, PA);
    if (w < NWAVE - 1 && lane == 63)
      recs[m] = make_float4(A * r.x, fmaf(A, r.y, Bv), PArec, 0.0f);
    // e = shr1(inclusive entry, fill=E)  ==  fmaf(Aex,E,Bex) lane-wise
    float eI = fmaf(A, E, Bv);
    float e = wave_shr1(eI, E);
    float U = fminf(fmaxf(e, 0.0f), w8);  // upper clamp subsumed by w8<=1
    float p = c2r * U;
    w8 -= p;
    *pO = p;
  };

  // ---- 8-row systolic step (one barrier per step) ----
  auto oct_step = [&](int t, int k, float (&WX)[8], float (&WM)[8],
                      const float (&RX)[8], const float (&RM)[8]) {
    const int q = t - w;
    if ((unsigned)q < (unsigned)NOCT) {  // wave-uniform
      const int m = 8 * q;
      // read all 8 predecessor cum records (published 1 step ago,
      // ordered by the intervening barrier)
      float4 r[8];
#pragma unroll
      for (int i = 0; i < 8; ++i) r[i] = make_float4(1.0f, 0.0f, 0.0f, 0.0f);
      if (w > 0) {
#pragma unroll
        for (int i = 0; i < 8; ++i) r[i] = recs[m + i];
      }
      // issue next octet's global loads (octet q+2) into slot registers
      const float* pxk = px + (size_t)(8 * k) * NDIM;
      const float* pmk = pm + (size_t)(8 * k) * NDIM;
#pragma unroll
      for (int i = 0; i < 8; ++i) {
        WX[i] = pxk[(size_t)i * NDIM];
        WM[i] = pmk[(size_t)i * NDIM];
      }
      // octet q+1 prep is fused into the 8 prefix scans below
      float c2n[8], oc2n[8];
      float* pok = po + (size_t)(8 * k) * NDIM;
#pragma unroll
      for (int i = 0; i < 8; ++i) {
        row_fast(m + i, r[i], c2c[i], oc2c[i], RX[i], RM[i], c2n[i], oc2n[i],
                 pok + (size_t)i * NDIM);
        t8 = (i < 7 ? c2c[i + 1] : c2n[0]) * w8;
      }
#pragma unroll
      for (int i = 0; i < 8; ++i) {
        c2c[i] = c2n[i];
        oc2c[i] = oc2n[i];
      }
    }
    wg_barrier();
  };

  // fast phase: steps t = 0 .. 62 (wave w active for t in [w, w+56))
#pragma unroll 1
  for (int t = 0; t < NOCT + NWAVE; t += 2) {
    oct_step(t + 0, 0, Ax, Am, Bx, Bm);
    oct_step(t + 1, 1, Bx, Bm, Ax, Am);
    px += 16 * NDIM;
    pm += 16 * NDIM;
    po += 16 * NDIM;
  }
  // all waves synced by the final step barrier; recs no longer used.
  // c2c[0..7] hold rows 448..455 constants (prepped at q=55);
  // t8 = c2(448) * w8 from the last fast step's tail.

  // ---- bridge: row-448 constants + fu/S; reload rows 449..451 into
  // FULL-phase single-row slots (L2-hot, one-time). ----
  float fx0, fm0, fx1, fm1, fx2, fm2, fx3, fm3;
  {
    float m448 = mb[(size_t)448 * NDIM];
    fx1 = xb[(size_t)449 * NDIM];
    fm1 = mb[(size_t)449 * NDIM];
    fx2 = xb[(size_t)450 * NDIM];
    fm2 = mb[(size_t)450 * NDIM];
    fx3 = xb[(size_t)451 * NDIM];
    fm3 = mb[(size_t)451 * NDIM];
    fx0 = fx1;  // defined; overwritten at m=448 step
    fm0 = fm1;
    c2 = c2c[0];
    oc2 = oc2c[0];
    c1 = m448 - c2;
    float om = 1.0f - m448;
    fu = fmaxf(w8 - om, 0.0f);
    S = fu;
  }

  // ---- FULL row body: proven 2-barrier exchange (backward dep on S) ----
  auto row_full = [&](int m, float& WX, float& WM, const float& RX,
                      const float& RM) {
    const size_t nro = (size_t)((m + 4) & (NDIM - 1)) * NDIM;
    WX = xb[nro];
    WM = mb[nro];

    // local wave scans (chain head); independent scans interleaved
    float PS = S, PA = t8;
    prefix_inc2(PS, PA);

    if (lane == 63) {
      ex_sa[w] = PA;  // wave-inclusive totals
      ex_S[w] = PS;
    }
    wg_barrier();  // bar1: publish scan totals

    float4 sl = *(const float4*)&ex_sa[0];
    float4 sh = *(const float4*)&ex_sa[4];
    float4 Sl = *(const float4*)&ex_S[0];
    float4 Sh = *(const float4*)&ex_S[4];
    float off_sa = 0.0f, off_S = 0.0f;
    if (w > 0) { off_sa += sl.x; off_S += Sl.x; }
    if (w > 1) { off_sa += sl.y; off_S += Sl.y; }
    if (w > 2) { off_sa += sl.z; off_S += Sl.z; }
    if (w > 3) { off_sa += sl.w; off_S += Sl.w; }
    if (w > 4) { off_sa += sh.x; off_S += Sh.x; }
    if (w > 5) { off_sa += sh.y; off_S += Sh.y; }
    if (w > 6) { off_sa += sh.z; off_S += Sh.z; }
    float Tg =
        ((Sl.x + Sl.y) + (Sl.z + Sl.w)) + ((Sh.x + Sh.y) + (Sh.z + Sh.w));

    float uin = fmaxf(1.0f - (off_sa + (PA - t8)), 0.0f);
    float R_ = (Tg - off_S) - PS;  // future mass strictly after this lane
    float nc1m = -c1 * R_;         // per-lane suf == 0 at 1 col/lane

    // branch prediction (1 cell)
    bool pW = w8 < uin;
    float aP = pW ? 1.0f : oc2;
    float bP = pW ? (-t8) : 0.0f;
    bool pL = (uin - R_) > 0.0f;
    if (pL) {
      aP -= c1;
      bP -= nc1m;
    }

    // wave affine scan
    float A = aP, Bv = bP;
    aff_scan(A, Bv);
    float Aex = wave_shr1(A, 1.0f);
    float Bex = wave_shr1(Bv, 0.0f);

    if (lane == 63) {
      ex_A[w] = A;  // wave-inclusive composition
      ex_B[w] = Bv;
    }
    wg_barrier();  // bar2: publish affine totals

    float4 Al = *(const float4*)&ex_A[0];
    float4 Ah = *(const float4*)&ex_A[4];
    float4 Bl = *(const float4*)&ex_B[0];
    float4 Bh = *(const float4*)&ex_B[4];
    float E = 1.0f;
    if (w > 0) E = fmaf(Al.x, E, Bl.x);
    if (w > 1) E = fmaf(Al.y, E, Bl.y);
    if (w > 2) E = fmaf(Al.z, E, Bl.z);
    if (w > 3) E = fmaf(Al.w, E, Bl.w);
    if (w > 4) E = fmaf(Ah.x, E, Bh.x);
    if (w > 5) E = fmaf(Ah.y, E, Bh.y);
    if (w > 6) E = fmaf(Ah.z, E, Bh.z);
    float e = fminf(fmaxf(fmaf(Aex, E, Bex), 0.0f), 1.0f);  // lane entry

    // row m+1 x-only prep (off-chain)
    float sg = __builtin_amdgcn_rcpf(1.0f + __expf(-RX));
    float c2n = RM * sg;
    float oc2n = 1.0f - c2n;
    float c1n = RM - c2n;
    float omn = 1.0f - RM;

    // TRUE-branch output
    float U = fminf(e, w8);
    float g = fmaxf(fmaf(c1, e, nc1m), 0.0f);
    float p = fmaf(c2, U, g);
    w8 -= p;
    ob[(size_t)m * NDIM] = p;

    // next row's scan inputs
    t8 = c2n * w8;
    fu = fmaxf(w8 - omn, 0.0f);
    S = fu;
    c2 = c2n;
    oc2 = oc2n;
    c1 = c1n;
  };

#pragma unroll 1
  for (int m = NFAST; m < NDIM; m += 4) {
    row_full(m + 0, fx0, fm0, fx1, fm1);
    row_full(m + 1, fx1, fm1, fx2, fm2);
    row_full(m + 2, fx2, fm2, fx3, fm3);
    row_full(m + 3, fx3, fm3, fx0, fm0);
  }
}

extern "C" void kernel_launch(void* const* d_in, const int* in_sizes, int n_in,
                              void* d_out, int out_size, void* d_ws,
                              size_t ws_size, hipStream_t stream) {
  const float* x = (const float*)d_in[0];
  const float* xmask = (const float*)d_in[1];
  float* out = (float*)d_out;
  (void)in_sizes;
  (void)n_in;
  (void)out_size;
  (void)d_ws;
  (void)ws_size;
  hipLaunchKernelGGL(sb_kernel, dim3(NBATCH), dim3(512), 0, stream, x, xmask,
                     out);
}